// Round 1
// baseline (267.173 us; speedup 1.0000x reference)
//
#include <hip/hip_runtime.h>
#include <cmath>

#define NQ 16
#define NT 8

typedef float f32x4 __attribute__((ext_vector_type(4)));

// order-preserving float->u32 (total order ascending)
__device__ __forceinline__ unsigned ordf(float x) {
    unsigned u = __float_as_uint(x);
    return u ^ ((unsigned)((int)u >> 31) | 0x80000000u);
}
// inverse; 0xFFFFFFFF (empty sentinel) -> NaN so ordered compares are false
__device__ __forceinline__ float unordf(unsigned k) {
    unsigned m = (~(unsigned)((int)k >> 31)) | 0x80000000u;
    return __uint_as_float(k ^ m);
}
__device__ __forceinline__ unsigned umin2(unsigned a, unsigned b) { return a < b ? a : b; }
__device__ __forceinline__ unsigned umax2(unsigned a, unsigned b) { return a > b ? a : b; }

// lane^1 exchange via DPP quad_perm [1,0,3,2] — single VALU instruction.
// Replaces HIP __shfl_xor, which lowers to ds_bpermute (LDS pipe) plus
// lane-index VALU math. Pairs (2k, 2k+1) sit inside one quad, so quad_perm
// is exact for the 2-lane-per-row layout.
__device__ __forceinline__ unsigned dpp_xor1_u(unsigned x) {
    return (unsigned)__builtin_amdgcn_mov_dpp((int)x, 0xB1, 0xF, 0xF, true);
}
__device__ __forceinline__ float dpp_xor1_f(float x) {
    return __uint_as_float(dpp_xor1_u(__float_as_uint(x)));
}

// Exact reference-parity path (rare): recompute the whole row with the
// correctly-rounded double-exp sigmoid and exact float dedup (validated
// bit-exact vs reference in earlier rounds, absmax 0.0). Unchanged.
__device__ __noinline__ unsigned exact_mask(
    const float* __restrict__ pred_logits,
    const float* __restrict__ pred_disp,
    const float* __restrict__ targets,
    size_t b)
{
    float tg[NT];
#pragma unroll
    for (int t = 0; t < NT; ++t) {
        float v = targets[b * NT + t];
        tg[t] = (v == 0.0f) ? 1000000.0f : v;
    }
    float C[NQ];
    int   ind[NQ];
#pragma unroll
    for (int n = 0; n < NQ; ++n) {
        float d = pred_disp[b * NQ + n];
        float best = fabsf(d - tg[0]);
        int bi = 0;
#pragma unroll
        for (int t = 1; t < NT; ++t) {
            float e = fabsf(d - tg[t]);
            if (e < best) { best = e; bi = t; }   // strict <: first target wins
        }
        float sig = (float)(1.0 / (1.0 + exp(-(double)pred_logits[b * NQ + n])));
        C[n] = (-sig) + best;                     // same op order as reference
        ind[n] = bi;
    }
    unsigned mask = 0u;
#pragma unroll
    for (int t = 0; t < NT; ++t) {
        int w = 31;
        float bc = 3.0e38f;
#pragma unroll
        for (int n = 0; n < NQ; ++n) {
            bool upd = (ind[n] == t) && (C[n] < bc);  // strict <: first query wins
            bc = upd ? C[n] : bc;
            w  = upd ? n : w;
        }
        mask |= (1u << w);
    }
    return mask;
}

// TWO lanes per row: lane j of a pair owns queries 8j..8j+7.
//  - disp/logits: 2x f32x4 per lane (32 B), consecutive lanes 32 B apart —
//    both halves of every cache line consumed by the instruction pair.
//  - targets: 16 B/lane PERFECTLY coalesced ((f32x4*)targets)[gid], one DPP
//    half-swap shares them across the pair.
//  - dedup: local best/2nd over 8 queries, then ONE DPP reduce round
//    (vs 2 shfl rounds before) — halves the replicated per-row dedup work
//    and covers 32 rows/wave instead of 16.
//  - outputs: nontemporal 16 B stores — write-only data bypasses L2/L3 so
//    the ~168 MB input set stays L3-resident across dispatches.
__global__ __launch_bounds__(256) void nearest_matcher_kernel(
    const float* __restrict__ pred_logits,
    const float* __restrict__ pred_disp,
    const float* __restrict__ targets,
    float* __restrict__ out_idx,
    float* __restrict__ out_lab,
    int B)
{
    const size_t gid = (size_t)blockIdx.x * blockDim.x + threadIdx.x;
    const size_t b   = gid >> 1;          // row
    const int    j   = (int)(gid & 1);    // lane-in-pair: owns queries 8j..8j+7
    if (b >= (size_t)B) return;

    const float BIGF = 1000000.0f;

    // ---- coalesced loads ----
    f32x4 d0 = ((const f32x4*)pred_disp)[gid * 2];
    f32x4 d1 = ((const f32x4*)pred_disp)[gid * 2 + 1];
    f32x4 l0 = ((const f32x4*)pred_logits)[gid * 2];
    f32x4 l1 = ((const f32x4*)pred_logits)[gid * 2 + 1];
    f32x4 t4 = ((const f32x4*)targets)[gid];          // my half of the 8 targets

    // sentinel-replace my half, swap halves across the pair (lane ^ 1)
    float tv[4] = {t4.x, t4.y, t4.z, t4.w};
#pragma unroll
    for (int i = 0; i < 4; ++i) tv[i] = (tv[i] == 0.0f) ? BIGF : tv[i];
    float ov[4];
#pragma unroll
    for (int i = 0; i < 4; ++i) ov[i] = dpp_xor1_f(tv[i]);

    float tg[NT];
#pragma unroll
    for (int i = 0; i < 4; ++i) {
        tg[i]     = (j == 0) ? tv[i] : ov[i];
        tg[4 + i] = (j == 0) ? ov[i] : tv[i];
    }

    // ---- my 8 queries: exact argmin over 8 targets + fast-sigmoid key ----
    float dv[8] = {d0.x, d0.y, d0.z, d0.w, d1.x, d1.y, d1.z, d1.w};
    float lv[8] = {l0.x, l0.y, l0.z, l0.w, l1.x, l1.y, l1.z, l1.w};
    int      ind[8];
    unsigned qk[8];
#pragma unroll
    for (int i = 0; i < 8; ++i) {
        float d = dv[i];
        float best = fabsf(d - tg[0]);
        int bi = 0;
#pragma unroll
        for (int t = 1; t < NT; ++t) {
            float e = fabsf(d - tg[t]);
            if (e < best) { best = e; bi = t; }   // exact: matches reference
        }
        ind[i] = bi;
        float sig = __builtin_amdgcn_rcpf(1.0f + __expf(-lv[i]));
        float C = best - sig;
        int n = 8 * j + i;                        // global query id
        qk[i] = (ordf(C) & ~31u) | (unsigned)n;   // key: C order + query id
    }

    // ---- per-target (best, 2nd-best): local over 8, one DPP round over pair ----
    unsigned mask = 0u;
    bool need_slow = false;
#pragma unroll
    for (int t = 0; t < NT; ++t) {
        unsigned bc  = (ind[0] == t) ? qk[0] : 0xFFFFFFFFu;
        unsigned bc2 = 0xFFFFFFFFu;
#pragma unroll
        for (int i = 1; i < 8; ++i) {
            unsigned x = (ind[i] == t) ? qk[i] : 0xFFFFFFFFu;
            unsigned hi = umax2(bc, x);
            bc  = umin2(bc, x);
            bc2 = umin2(bc2, hi);
        }
        // cross-pair merge (both lanes end with identical reduced values)
        {
            unsigned ob  = dpp_xor1_u(bc);
            unsigned ob2 = dpp_xor1_u(bc2);
            unsigned hi  = umax2(bc, ob);
            bc  = umin2(bc, ob);
            bc2 = umin2(umin2(bc2, ob2), hi);     // -> v_min3_u32
        }
        // guard in float domain; empty/singleton -> NaN -> compare false.
        // thr covers fast-sigmoid error + 5-bit key clearing at all C scales.
        float bcf  = unordf(bc);
        float bc2f = unordf(bc2);
        float thr  = fmaf(fabsf(bcf), 1.6e-5f, 2.0e-4f);
        need_slow = need_slow || ((bc2f - bcf) < thr);
        mask |= (1u << (bc & 31u));       // empty -> bit 31, ignored below
    }

    // whole pair agrees (reduced values identical) -> no intra-pair divergence
    if (__builtin_expect(need_slow, 0))
        mask = exact_mask(pred_logits, pred_disp, targets, b);

    // ---- emit my 8 queries: 2x16 B nontemporal, contiguous across lanes ----
    f32x4 oi0, oi1, ol0, ol1;
    oi0.x = (float)ind[0]; oi0.y = (float)ind[1];
    oi0.z = (float)ind[2]; oi0.w = (float)ind[3];
    oi1.x = (float)ind[4]; oi1.y = (float)ind[5];
    oi1.z = (float)ind[6]; oi1.w = (float)ind[7];
    const int base = 8 * j;
    ol0.x = (float)((mask >> (base + 0)) & 1u);
    ol0.y = (float)((mask >> (base + 1)) & 1u);
    ol0.z = (float)((mask >> (base + 2)) & 1u);
    ol0.w = (float)((mask >> (base + 3)) & 1u);
    ol1.x = (float)((mask >> (base + 4)) & 1u);
    ol1.y = (float)((mask >> (base + 5)) & 1u);
    ol1.z = (float)((mask >> (base + 6)) & 1u);
    ol1.w = (float)((mask >> (base + 7)) & 1u);

    __builtin_nontemporal_store(oi0, ((f32x4*)out_idx) + gid * 2);
    __builtin_nontemporal_store(oi1, ((f32x4*)out_idx) + gid * 2 + 1);
    __builtin_nontemporal_store(ol0, ((f32x4*)out_lab) + gid * 2);
    __builtin_nontemporal_store(ol1, ((f32x4*)out_lab) + gid * 2 + 1);
}

extern "C" void kernel_launch(void* const* d_in, const int* in_sizes, int n_in,
                              void* d_out, int out_size, void* d_ws, size_t ws_size,
                              hipStream_t stream) {
    const float* pred_logits = (const float*)d_in[0];
    const float* pred_disp   = (const float*)d_in[1];
    const float* targets     = (const float*)d_in[2];

    int B = in_sizes[0] / NQ;

    float* out_idx = (float*)d_out;              // indices [B, NQ] flat, first
    float* out_lab = out_idx + (size_t)B * NQ;   // labels  [B, NQ] flat, second

    const int threads = 256;
    const size_t total = (size_t)B * 2;          // 2 lanes per row
    const int blocks = (int)((total + threads - 1) / threads);
    hipLaunchKernelGGL(nearest_matcher_kernel, dim3(blocks), dim3(threads), 0, stream,
                       pred_logits, pred_disp, targets, out_idx, out_lab, B);
}